// Round 5
// baseline (719.131 us; speedup 1.0000x reference)
//
#include <hip/hip_runtime.h>

#define NN 50000
#define NE 800000
#define ETOT (NE + NN)

typedef _Float16 f16;
typedef _Float16 v8h __attribute__((ext_vector_type(8)));
typedef float v4f __attribute__((ext_vector_type(4)));

// fragment-layout index for a 64x64 matrix, mfma_f32_16x16x32 B-operand:
// FR[(((nb*2+kb)*4+q)*16+p)*8 + i] = W[(kb*32+q*8+i)*64 + nb*16+p]
__device__ __forceinline__ int fr_off(int kb, int nb, int q, int p) {
  return (((nb * 2 + kb) * 4 + q) * 16 + p) * 8;
}

// ---------------- weight pre-conversion to f16 fragment layout ----------------
// 8 64x64 matrices + Wp1 (6x64, K-padded to 32: kb=0 only, 4 frags)

__global__ __launch_bounds__(256) void k_wprep(
    const float* __restrict__ W_in, const float* __restrict__ W_src,
    const float* __restrict__ W_dst, const float* __restrict__ W_lin,
    const float* __restrict__ W_out, const float* __restrict__ Wp2,
    const float* __restrict__ Wa1, const float* __restrict__ Wa2,
    const float* __restrict__ Wp1, f16* __restrict__ FR) {
  const int t = blockIdx.x * 256 + threadIdx.x;
  if (t < 8 * 4096) {
    const float* Ws[8] = {W_in, W_src, W_dst, W_lin, W_out, Wp2, Wa1, Wa2};
    const int m = t >> 12, idx = t & 4095;
    const int i = idx & 7, p = (idx >> 3) & 15, q = (idx >> 7) & 3;
    const int kb = (idx >> 9) & 1, nb = (idx >> 10) & 3;
    FR[t] = (f16)Ws[m][(kb * 32 + q * 8 + i) * 64 + nb * 16 + p];
  } else if (t < 8 * 4096 + 2048) {
    const int idx = t - 8 * 4096;
    const int i = idx & 7, p = (idx >> 3) & 15, q = (idx >> 7) & 3, nb = idx >> 9;
    const int k = q * 8 + i;
    FR[t] = (k < 6) ? (f16)Wp1[k * 64 + nb * 16 + p] : (f16)0.f;
  }
}

// ---------------- CSR build ----------------

__global__ void k_deg_init(int* __restrict__ deg) {
  int i = blockIdx.x * 256 + threadIdx.x;
  if (i < NN) deg[i] = 1;  // self loop
}

__global__ void k_deg(const int* __restrict__ dst, int* __restrict__ deg) {
  int e = blockIdx.x * 256 + threadIdx.x;
  if (e < NE) atomicAdd(&deg[dst[e]], 1);
}

// exclusive scan over deg -> offsets[NN+1]; also writes self-loop + cursor (merged k_self)
__global__ void k_scan(const int* __restrict__ deg, int* __restrict__ offsets,
                       int* __restrict__ ssrc, int* __restrict__ cursor) {
  __shared__ int wsum[16];
  __shared__ int carry;
  const int t = threadIdx.x, lane = t & 63, w = t >> 6;
  if (t == 0) carry = 0;
  __syncthreads();
  for (int base = 0; base < NN; base += 1024) {
    const int i = base + t;
    int v = (i < NN) ? deg[i] : 0;
    int x = v;
#pragma unroll
    for (int d = 1; d < 64; d <<= 1) {
      int y = __shfl_up(x, d, 64);
      if (lane >= d) x += y;
    }
    if (lane == 63) wsum[w] = x;
    __syncthreads();
    if (t < 16) {
      int z = wsum[t];
#pragma unroll
      for (int d = 1; d < 16; d <<= 1) {
        int y = __shfl_up(z, d, 64);
        if (t >= d) z += y;
      }
      wsum[t] = z;
    }
    __syncthreads();
    const int cb = carry;
    const int prev = (w > 0) ? wsum[w - 1] : 0;
    if (i < NN) {
      const int off = cb + prev + x - v;  // exclusive
      offsets[i] = off;
      ssrc[off] = i;        // self loop first in segment
      cursor[i] = off + 1;
    }
    const int ctot = wsum[15];
    __syncthreads();
    if (t == 0) carry = cb + ctot;
    __syncthreads();
  }
  if (t == 0) offsets[NN] = carry;
}

__global__ void k_scatter(const int* __restrict__ src, const int* __restrict__ dst,
                          int* __restrict__ cursor, int* __restrict__ ssrc) {
  int e = blockIdx.x * 256 + threadIdx.x;
  if (e < NE) {
    int p = atomicAdd(&cursor[dst[e]], 1);
    ssrc[p] = src[e];
  }
}

// ---------------- node projections (MFMA): h; a_src/a_dst/v; Q = pos@Wp1 ----------

__global__ __launch_bounds__(256, 2) void k_node(
    const float* __restrict__ x, const float* __restrict__ pos,
    const float* __restrict__ b_in, const f16* __restrict__ FR,
    float* __restrict__ a_dst, float* __restrict__ vv,
    f16* __restrict__ asrch, f16* __restrict__ Qh) {
  __shared__ f16 lds[4][16 * 72];
  const int lane = threadIdx.x & 63, w = threadIdx.x >> 6;
  const int q = lane >> 4, p = lane & 15;
  const int base = (blockIdx.x * 4 + w) * 16;
  if (base >= NN) return;
  const f16* FWin = FR;                 // m=0
  const f16* FWsrc = FR + 1 * 4096;     // m=1
  const f16* FWdst = FR + 2 * 4096;     // m=2
  const f16* FWlin = FR + 3 * 4096;     // m=3
  const f16* FWp1 = FR + 8 * 4096;      // kb=0 only

  v8h xa[2];
#pragma unroll
  for (int kb = 0; kb < 2; ++kb) {
    const float4 f0 = *(const float4*)(x + (base + p) * 64 + kb * 32 + q * 8);
    const float4 f1 = *(const float4*)(x + (base + p) * 64 + kb * 32 + q * 8 + 4);
    v8h a;
    a[0] = (f16)f0.x; a[1] = (f16)f0.y; a[2] = (f16)f0.z; a[3] = (f16)f0.w;
    a[4] = (f16)f1.x; a[5] = (f16)f1.y; a[6] = (f16)f1.z; a[7] = (f16)f1.w;
    xa[kb] = a;
  }
  // h = relu(x@W_in + b_in) -> LDS (C->A transpose)
#pragma unroll
  for (int nb = 0; nb < 4; ++nb) {
    v4f c = {0.f, 0.f, 0.f, 0.f};
    c = __builtin_amdgcn_mfma_f32_16x16x32_f16(xa[0], *(const v8h*)&FWin[fr_off(0, nb, q, p)], c, 0, 0, 0);
    c = __builtin_amdgcn_mfma_f32_16x16x32_f16(xa[1], *(const v8h*)&FWin[fr_off(1, nb, q, p)], c, 0, 0, 0);
    const float bi = b_in[p + 16 * nb];
#pragma unroll
    for (int r = 0; r < 4; ++r)
      lds[w][(q * 4 + r) * 72 + p + 16 * nb] = (f16)fmaxf(c[r] + bi, 0.f);
  }
  v8h hA[2];
#pragma unroll
  for (int kb = 0; kb < 2; ++kb)
    hA[kb] = *(const v8h*)&lds[w][p * 72 + kb * 32 + q * 8];

  // a_src (f16), a_dst (f32), v (f32)
#pragma unroll
  for (int nb = 0; nb < 4; ++nb) {
    v4f c = {0.f, 0.f, 0.f, 0.f};
    c = __builtin_amdgcn_mfma_f32_16x16x32_f16(hA[0], *(const v8h*)&FWsrc[fr_off(0, nb, q, p)], c, 0, 0, 0);
    c = __builtin_amdgcn_mfma_f32_16x16x32_f16(hA[1], *(const v8h*)&FWsrc[fr_off(1, nb, q, p)], c, 0, 0, 0);
#pragma unroll
    for (int r = 0; r < 4; ++r)
      asrch[(base + q * 4 + r) * 64 + p + 16 * nb] = (f16)c[r];
  }
#pragma unroll
  for (int nb = 0; nb < 4; ++nb) {
    v4f c = {0.f, 0.f, 0.f, 0.f};
    c = __builtin_amdgcn_mfma_f32_16x16x32_f16(hA[0], *(const v8h*)&FWdst[fr_off(0, nb, q, p)], c, 0, 0, 0);
    c = __builtin_amdgcn_mfma_f32_16x16x32_f16(hA[1], *(const v8h*)&FWdst[fr_off(1, nb, q, p)], c, 0, 0, 0);
#pragma unroll
    for (int r = 0; r < 4; ++r)
      a_dst[(base + q * 4 + r) * 64 + p + 16 * nb] = c[r];
  }
#pragma unroll
  for (int nb = 0; nb < 4; ++nb) {
    v4f c = {0.f, 0.f, 0.f, 0.f};
    c = __builtin_amdgcn_mfma_f32_16x16x32_f16(hA[0], *(const v8h*)&FWlin[fr_off(0, nb, q, p)], c, 0, 0, 0);
    c = __builtin_amdgcn_mfma_f32_16x16x32_f16(hA[1], *(const v8h*)&FWlin[fr_off(1, nb, q, p)], c, 0, 0, 0);
#pragma unroll
    for (int r = 0; r < 4; ++r)
      vv[(base + q * 4 + r) * 64 + p + 16 * nb] = c[r];
  }
  // Q = pos @ Wp1 (K padded to 32)
  v8h pa;
#pragma unroll
  for (int i = 0; i < 8; ++i) {
    const int k = q * 8 + i;
    pa[i] = (k < 6) ? (f16)pos[(base + p) * 6 + k] : (f16)0.f;
  }
#pragma unroll
  for (int nb = 0; nb < 4; ++nb) {
    const v8h b = *(const v8h*)&FWp1[(((nb * 4 + q) * 16) + p) * 8];
    v4f c = {0.f, 0.f, 0.f, 0.f};
    c = __builtin_amdgcn_mfma_f32_16x16x32_f16(pa, b, c, 0, 0, 0);
#pragma unroll
    for (int r = 0; r < 4; ++r)
      Qh[(base + q * 4 + r) * 64 + p + 16 * nb] = (f16)c[r];
  }
}

// ---------------- conv: wave = dst node, MFMA over 16-edge chunks ----------------
// Weight fragments staged in LDS (frees ~96 VGPRs -> 4 blocks/CU, ~50% occupancy).

__global__ __launch_bounds__(256, 4) void k_conv(
    const f16* __restrict__ Qh, const float* __restrict__ bp1,
    const f16* __restrict__ FRconv,  // Wp2|Wa1|Wa2 frag-layout, 12288 f16
    const float* __restrict__ bp2, const float* __restrict__ ba1,
    const float* __restrict__ ba2,
    const f16* __restrict__ asrch, const float* __restrict__ a_dst,
    const float* __restrict__ v,
    const int* __restrict__ offsets, const int* __restrict__ ssrc,
    float* __restrict__ o_pt) {
  __shared__ f16 wfr[12288];      // 24 KB: Wp2, Wa1, Wa2 fragment images
  __shared__ f16 tbuf[4][16 * 72];  // per-wave transpose buffer (reused)
  const int t = threadIdx.x;
#pragma unroll
  for (int it = 0; it < 6; ++it)
    *(uint4*)&wfr[(it * 256 + t) * 8] = *(const uint4*)&FRconv[(it * 256 + t) * 8];
  __syncthreads();

  const int lane = t & 63, w = t >> 6;
  const int q = lane >> 4, p = lane & 15;
  const int n = blockIdx.x * 4 + w;  // grid = NN/4 exactly

  float bp2C[4], ba1C[4], ba2C[4];
#pragma unroll
  for (int nb = 0; nb < 4; ++nb) {
    bp2C[nb] = bp2[p + 16 * nb];
    ba1C[nb] = ba1[p + 16 * nb];
    ba2C[nb] = ba2[p + 16 * nb];
  }
  // node-i quantities in A-layout channels (ch = kb*32 + q*8 + i)
  v8h Qi8[2];
  float adcA[16];
#pragma unroll
  for (int kb = 0; kb < 2; ++kb) {
    const v8h qv = *(const v8h*)(Qh + n * 64 + kb * 32 + q * 8);
    const float4 b0 = *(const float4*)(bp1 + kb * 32 + q * 8);
    const float4 b1 = *(const float4*)(bp1 + kb * 32 + q * 8 + 4);
    v8h a;
    a[0] = (f16)((float)qv[0] + b0.x); a[1] = (f16)((float)qv[1] + b0.y);
    a[2] = (f16)((float)qv[2] + b0.z); a[3] = (f16)((float)qv[3] + b0.w);
    a[4] = (f16)((float)qv[4] + b1.x); a[5] = (f16)((float)qv[5] + b1.y);
    a[6] = (f16)((float)qv[6] + b1.z); a[7] = (f16)((float)qv[7] + b1.w);
    Qi8[kb] = a;
    const float4 d0 = *(const float4*)(a_dst + n * 64 + kb * 32 + q * 8);
    const float4 d1 = *(const float4*)(a_dst + n * 64 + kb * 32 + q * 8 + 4);
    adcA[kb * 8 + 0] = d0.x; adcA[kb * 8 + 1] = d0.y;
    adcA[kb * 8 + 2] = d0.z; adcA[kb * 8 + 3] = d0.w;
    adcA[kb * 8 + 4] = d1.x; adcA[kb * 8 + 5] = d1.y;
    adcA[kb * 8 + 6] = d1.z; adcA[kb * 8 + 7] = d1.w;
  }
  const int e0 = __builtin_amdgcn_readfirstlane(offsets[n]);
  const int e1 = __builtin_amdgcn_readfirstlane(offsets[n + 1]);
  const int cnt = e1 - e0;

  float m_[4], s_[4], ac_[4];
#pragma unroll
  for (int nb = 0; nb < 4; ++nb) { m_[nb] = 0.f; s_[nb] = 0.f; ac_[nb] = 0.f; }

  for (int cb = 0; cb < cnt; cb += 16) {
    const int jA = ssrc[e0 + min(cb + p, cnt - 1)];  // A-layout edge = p
    int jC[4]; bool okC[4];
#pragma unroll
    for (int r = 0; r < 4; ++r) {  // C-layout edges = q*4+r
      const int tt = cb + q * 4 + r;
      okC[r] = tt < cnt;
      jC[r] = ssrc[e0 + min(tt, cnt - 1)];
    }
    // hp = relu((Qi+bp1) - Qj)  in A layout, packed f16
    v8h uA[2];
#pragma unroll
    for (int kb = 0; kb < 2; ++kb) {
      const v8h qj = *(const v8h*)(Qh + jA * 64 + kb * 32 + q * 8);
      v8h a;
#pragma unroll
      for (int i = 0; i < 8; ++i) {
        const f16 d = Qi8[kb][i] - qj[i];
        a[i] = d > (f16)0 ? d : (f16)0;
      }
      uA[kb] = a;
    }
    // delta = relu(hp @ Wp2 + bp2)  (C layout); stash + LDS transpose
    float deltaC[16];
#pragma unroll
    for (int nb = 0; nb < 4; ++nb) {
      v4f c = {0.f, 0.f, 0.f, 0.f};
      c = __builtin_amdgcn_mfma_f32_16x16x32_f16(uA[0], *(const v8h*)&wfr[fr_off(0, nb, q, p)], c, 0, 0, 0);
      c = __builtin_amdgcn_mfma_f32_16x16x32_f16(uA[1], *(const v8h*)&wfr[fr_off(1, nb, q, p)], c, 0, 0, 0);
#pragma unroll
      for (int r = 0; r < 4; ++r) {
        const float d = fmaxf(c[r] + bp2C[nb], 0.f);
        deltaC[nb * 4 + r] = d;
        tbuf[w][(q * 4 + r) * 72 + p + 16 * nb] = (f16)d;
      }
    }
    // u = a_dst_i - a_src_j + delta  in A layout (f32 math, f16 out)
#pragma unroll
    for (int kb = 0; kb < 2; ++kb) {
      const v8h dj = *(const v8h*)&tbuf[w][p * 72 + kb * 32 + q * 8];
      const v8h aj = *(const v8h*)(asrch + jA * 64 + kb * 32 + q * 8);
      v8h a;
#pragma unroll
      for (int i = 0; i < 8; ++i)
        a[i] = (f16)((adcA[kb * 8 + i] - (float)aj[i]) + (float)dj[i]);
      uA[kb] = a;
    }
    // ha = relu(u @ Wa1 + ba1) -> LDS transpose -> A layout
#pragma unroll
    for (int nb = 0; nb < 4; ++nb) {
      v4f c = {0.f, 0.f, 0.f, 0.f};
      c = __builtin_amdgcn_mfma_f32_16x16x32_f16(uA[0], *(const v8h*)&wfr[4096 + fr_off(0, nb, q, p)], c, 0, 0, 0);
      c = __builtin_amdgcn_mfma_f32_16x16x32_f16(uA[1], *(const v8h*)&wfr[4096 + fr_off(1, nb, q, p)], c, 0, 0, 0);
#pragma unroll
      for (int r = 0; r < 4; ++r)
        tbuf[w][(q * 4 + r) * 72 + p + 16 * nb] = (f16)fmaxf(c[r] + ba1C[nb], 0.f);
    }
#pragma unroll
    for (int kb = 0; kb < 2; ++kb)
      uA[kb] = *(const v8h*)&tbuf[w][p * 72 + kb * 32 + q * 8];
    // alpha = relu(ha @ Wa2 + ba2)  (C layout) + masked online softmax
#pragma unroll
    for (int nb = 0; nb < 4; ++nb) {
      v4f c = {0.f, 0.f, 0.f, 0.f};
      c = __builtin_amdgcn_mfma_f32_16x16x32_f16(uA[0], *(const v8h*)&wfr[8192 + fr_off(0, nb, q, p)], c, 0, 0, 0);
      c = __builtin_amdgcn_mfma_f32_16x16x32_f16(uA[1], *(const v8h*)&wfr[8192 + fr_off(1, nb, q, p)], c, 0, 0, 0);
      float al[4];
#pragma unroll
      for (int r = 0; r < 4; ++r)
        al[r] = okC[r] ? fmaxf(c[r] + ba2C[nb], 0.f) : -3.0e38f;
      float mn = m_[nb];
#pragma unroll
      for (int r = 0; r < 4; ++r) mn = fmaxf(mn, al[r]);
      const float sc = __expf(m_[nb] - mn);
      float ss = s_[nb] * sc;
      float aa = ac_[nb] * sc;
#pragma unroll
      for (int r = 0; r < 4; ++r) {
        const float wv = __expf(al[r] - mn);  // 0 for masked edges
        const float vj = v[jC[r] * 64 + p + 16 * nb];
        ss += wv;
        aa = fmaf(wv, vj + deltaC[nb * 4 + r], aa);
      }
      m_[nb] = mn; s_[nb] = ss; ac_[nb] = aa;
    }
  }
  // merge per-quad partial softmax states (channels identical across quads)
#pragma unroll
  for (int st = 16; st <= 32; st <<= 1) {
#pragma unroll
    for (int nb = 0; nb < 4; ++nb) {
      const float mo = __shfl_xor(m_[nb], st, 64);
      const float so = __shfl_xor(s_[nb], st, 64);
      const float ao = __shfl_xor(ac_[nb], st, 64);
      const float mn = fmaxf(m_[nb], mo);
      const float c1 = __expf(m_[nb] - mn), c2 = __expf(mo - mn);
      s_[nb] = s_[nb] * c1 + so * c2;
      ac_[nb] = ac_[nb] * c1 + ao * c2;
      m_[nb] = mn;
    }
  }
  if (q == 0) {
#pragma unroll
    for (int nb = 0; nb < 4; ++nb)
      o_pt[n * 64 + p + 16 * nb] = ac_[nb] / (s_[nb] + 1e-16f);
  }
}

// ---------------- epilogue (MFMA): out = relu(o_pt @ W_out + b_out) + x ------------

__global__ __launch_bounds__(256, 2) void k_out(
    const float* __restrict__ o_pt, const f16* __restrict__ FR,
    const float* __restrict__ b_out, const float* __restrict__ x,
    float* __restrict__ out) {
  const int lane = threadIdx.x & 63, w = threadIdx.x >> 6;
  const int q = lane >> 4, p = lane & 15;
  const int base = (blockIdx.x * 4 + w) * 16;
  if (base >= NN) return;
  const f16* FWout = FR + 4 * 4096;  // m=4
  v8h oa[2];
#pragma unroll
  for (int kb = 0; kb < 2; ++kb) {
    const float4 f0 = *(const float4*)(o_pt + (base + p) * 64 + kb * 32 + q * 8);
    const float4 f1 = *(const float4*)(o_pt + (base + p) * 64 + kb * 32 + q * 8 + 4);
    v8h a;
    a[0] = (f16)f0.x; a[1] = (f16)f0.y; a[2] = (f16)f0.z; a[3] = (f16)f0.w;
    a[4] = (f16)f1.x; a[5] = (f16)f1.y; a[6] = (f16)f1.z; a[7] = (f16)f1.w;
    oa[kb] = a;
  }
#pragma unroll
  for (int nb = 0; nb < 4; ++nb) {
    v4f c = {0.f, 0.f, 0.f, 0.f};
    c = __builtin_amdgcn_mfma_f32_16x16x32_f16(oa[0], *(const v8h*)&FWout[fr_off(0, nb, q, p)], c, 0, 0, 0);
    c = __builtin_amdgcn_mfma_f32_16x16x32_f16(oa[1], *(const v8h*)&FWout[fr_off(1, nb, q, p)], c, 0, 0, 0);
    const float bo = b_out[p + 16 * nb];
#pragma unroll
    for (int r = 0; r < 4; ++r) {
      const int idx = (base + q * 4 + r) * 64 + p + 16 * nb;
      out[idx] = fmaxf(c[r] + bo, 0.f) + x[idx];
    }
  }
}

// ---------------- launch ----------------

extern "C" void kernel_launch(void* const* d_in, const int* in_sizes, int n_in,
                              void* d_out, int out_size, void* d_ws, size_t ws_size,
                              hipStream_t stream) {
  const float* x     = (const float*)d_in[0];
  const float* pos   = (const float*)d_in[1];
  const int*   ei    = (const int*)d_in[2];
  const float* W_in  = (const float*)d_in[3];
  const float* b_in  = (const float*)d_in[4];
  const float* W_out = (const float*)d_in[5];
  const float* b_out = (const float*)d_in[6];
  const float* W_lin = (const float*)d_in[7];
  const float* W_src = (const float*)d_in[8];
  const float* W_dst = (const float*)d_in[9];
  const float* Wp1   = (const float*)d_in[10];
  const float* bp1   = (const float*)d_in[11];
  const float* Wp2   = (const float*)d_in[12];
  const float* bp2   = (const float*)d_in[13];
  const float* Wa1   = (const float*)d_in[14];
  const float* ba1   = (const float*)d_in[15];
  const float* Wa2   = (const float*)d_in[16];
  const float* ba2   = (const float*)d_in[17];

  float* a_dst = (float*)d_ws;                 // NN*64 f32
  float* vv    = a_dst + NN * 64;              // NN*64 f32
  float* o_pt  = vv + NN * 64;                 // NN*64 f32
  f16*  Qh     = (f16*)(o_pt + NN * 64);       // NN*64 f16
  f16*  asrch  = Qh + NN * 64;                 // NN*64 f16
  f16*  FR     = asrch + NN * 64;              // 8*4096 + 2048 f16 (16B aligned)
  int*  deg    = (int*)(FR + 8 * 4096 + 2048); // NN
  int* offsets = deg + NN;                     // NN+1
  int* cursor  = offsets + NN + 1;             // NN
  int* ssrc    = cursor + NN;                  // ETOT

  const int* esrc = ei;
  const int* edst = ei + NE;

  k_wprep<<<(8 * 4096 + 2048 + 255) / 256, 256, 0, stream>>>(
      W_in, W_src, W_dst, W_lin, W_out, Wp2, Wa1, Wa2, Wp1, FR);
  k_deg_init<<<(NN + 255) / 256, 256, 0, stream>>>(deg);
  k_node<<<(NN / 16 + 3) / 4, 256, 0, stream>>>(x, pos, b_in, FR, a_dst, vv, asrch, Qh);
  k_deg<<<(NE + 255) / 256, 256, 0, stream>>>(edst, deg);
  k_scan<<<1, 1024, 0, stream>>>(deg, offsets, ssrc, cursor);
  k_scatter<<<(NE + 255) / 256, 256, 0, stream>>>(esrc, edst, cursor, ssrc);
  k_conv<<<NN / 4, 256, 0, stream>>>(Qh, bp1, FR + 5 * 4096, bp2, ba1, ba2,
                                     asrch, a_dst, vv, offsets, ssrc, o_pt);
  k_out<<<(NN / 16 + 3) / 4, 256, 0, stream>>>(o_pt, FR, b_out, x, (float*)d_out);
}

// Round 6
// 583.050 us; speedup vs baseline: 1.2334x; 1.2334x over previous
//
#include <hip/hip_runtime.h>

#define NN 50000
#define NE 800000
#define ETOT (NE + NN)

typedef _Float16 f16;
typedef _Float16 v8h __attribute__((ext_vector_type(8)));
typedef float v4f __attribute__((ext_vector_type(4)));

// fragment-layout index for a 64x64 matrix, mfma_f32_16x16x32 B-operand:
// FR[(((nb*2+kb)*4+q)*16+p)*8 + i] = W[(kb*32+q*8+i)*64 + nb*16+p]
__device__ __forceinline__ int fr_off(int kb, int nb, int q, int p) {
  return (((nb * 2 + kb) * 4 + q) * 16 + p) * 8;
}

// ---------------- weight pre-conversion to f16 fragment layout ----------------
// 8 64x64 matrices + Wp1 (6x64, K-padded to 32: kb=0 only, 4 frags)

__global__ __launch_bounds__(256) void k_wprep(
    const float* __restrict__ W_in, const float* __restrict__ W_src,
    const float* __restrict__ W_dst, const float* __restrict__ W_lin,
    const float* __restrict__ W_out, const float* __restrict__ Wp2,
    const float* __restrict__ Wa1, const float* __restrict__ Wa2,
    const float* __restrict__ Wp1, f16* __restrict__ FR) {
  const int t = blockIdx.x * 256 + threadIdx.x;
  if (t < 8 * 4096) {
    const float* Ws[8] = {W_in, W_src, W_dst, W_lin, W_out, Wp2, Wa1, Wa2};
    const int m = t >> 12, idx = t & 4095;
    const int i = idx & 7, p = (idx >> 3) & 15, q = (idx >> 7) & 3;
    const int kb = (idx >> 9) & 1, nb = (idx >> 10) & 3;
    FR[t] = (f16)Ws[m][(kb * 32 + q * 8 + i) * 64 + nb * 16 + p];
  } else if (t < 8 * 4096 + 2048) {
    const int idx = t - 8 * 4096;
    const int i = idx & 7, p = (idx >> 3) & 15, q = (idx >> 7) & 3, nb = idx >> 9;
    const int k = q * 8 + i;
    FR[t] = (k < 6) ? (f16)Wp1[k * 64 + nb * 16 + p] : (f16)0.f;
  }
}

// ---------------- CSR build ----------------

__global__ void k_deg_init(int* __restrict__ deg) {
  int i = blockIdx.x * 256 + threadIdx.x;
  if (i < NN) deg[i] = 1;  // self loop
}

__global__ void k_deg(const int* __restrict__ dst, int* __restrict__ deg) {
  int e = blockIdx.x * 256 + threadIdx.x;
  if (e < NE) atomicAdd(&deg[dst[e]], 1);
}

// exclusive scan over deg -> offsets[NN+1]; also writes self-loop + cursor (merged k_self)
__global__ void k_scan(const int* __restrict__ deg, int* __restrict__ offsets,
                       int* __restrict__ ssrc, int* __restrict__ cursor) {
  __shared__ int wsum[16];
  __shared__ int carry;
  const int t = threadIdx.x, lane = t & 63, w = t >> 6;
  if (t == 0) carry = 0;
  __syncthreads();
  for (int base = 0; base < NN; base += 1024) {
    const int i = base + t;
    int v = (i < NN) ? deg[i] : 0;
    int x = v;
#pragma unroll
    for (int d = 1; d < 64; d <<= 1) {
      int y = __shfl_up(x, d, 64);
      if (lane >= d) x += y;
    }
    if (lane == 63) wsum[w] = x;
    __syncthreads();
    if (t < 16) {
      int z = wsum[t];
#pragma unroll
      for (int d = 1; d < 16; d <<= 1) {
        int y = __shfl_up(z, d, 64);
        if (t >= d) z += y;
      }
      wsum[t] = z;
    }
    __syncthreads();
    const int cb = carry;
    const int prev = (w > 0) ? wsum[w - 1] : 0;
    if (i < NN) {
      const int off = cb + prev + x - v;  // exclusive
      offsets[i] = off;
      ssrc[off] = i;        // self loop first in segment
      cursor[i] = off + 1;
    }
    const int ctot = wsum[15];
    __syncthreads();
    if (t == 0) carry = cb + ctot;
    __syncthreads();
  }
  if (t == 0) offsets[NN] = carry;
}

__global__ void k_scatter(const int* __restrict__ src, const int* __restrict__ dst,
                          int* __restrict__ cursor, int* __restrict__ ssrc) {
  int e = blockIdx.x * 256 + threadIdx.x;
  if (e < NE) {
    int p = atomicAdd(&cursor[dst[e]], 1);
    ssrc[p] = src[e];
  }
}

// ---------------- node projections (MFMA): h; a_src/a_dst/v; Q = pos@Wp1 ----------

__global__ __launch_bounds__(256, 2) void k_node(
    const float* __restrict__ x, const float* __restrict__ pos,
    const float* __restrict__ b_in, const f16* __restrict__ FR,
    float* __restrict__ a_dst, float* __restrict__ vv,
    f16* __restrict__ asrch, f16* __restrict__ Qh) {
  __shared__ f16 lds[4][16 * 72];
  const int lane = threadIdx.x & 63, w = threadIdx.x >> 6;
  const int q = lane >> 4, p = lane & 15;
  const int base = (blockIdx.x * 4 + w) * 16;
  if (base >= NN) return;
  const f16* FWin = FR;                 // m=0
  const f16* FWsrc = FR + 1 * 4096;     // m=1
  const f16* FWdst = FR + 2 * 4096;     // m=2
  const f16* FWlin = FR + 3 * 4096;     // m=3
  const f16* FWp1 = FR + 8 * 4096;      // kb=0 only

  v8h xa[2];
#pragma unroll
  for (int kb = 0; kb < 2; ++kb) {
    const float4 f0 = *(const float4*)(x + (base + p) * 64 + kb * 32 + q * 8);
    const float4 f1 = *(const float4*)(x + (base + p) * 64 + kb * 32 + q * 8 + 4);
    v8h a;
    a[0] = (f16)f0.x; a[1] = (f16)f0.y; a[2] = (f16)f0.z; a[3] = (f16)f0.w;
    a[4] = (f16)f1.x; a[5] = (f16)f1.y; a[6] = (f16)f1.z; a[7] = (f16)f1.w;
    xa[kb] = a;
  }
  // h = relu(x@W_in + b_in) -> LDS (C->A transpose)
#pragma unroll
  for (int nb = 0; nb < 4; ++nb) {
    v4f c = {0.f, 0.f, 0.f, 0.f};
    c = __builtin_amdgcn_mfma_f32_16x16x32_f16(xa[0], *(const v8h*)&FWin[fr_off(0, nb, q, p)], c, 0, 0, 0);
    c = __builtin_amdgcn_mfma_f32_16x16x32_f16(xa[1], *(const v8h*)&FWin[fr_off(1, nb, q, p)], c, 0, 0, 0);
    const float bi = b_in[p + 16 * nb];
#pragma unroll
    for (int r = 0; r < 4; ++r)
      lds[w][(q * 4 + r) * 72 + p + 16 * nb] = (f16)fmaxf(c[r] + bi, 0.f);
  }
  v8h hA[2];
#pragma unroll
  for (int kb = 0; kb < 2; ++kb)
    hA[kb] = *(const v8h*)&lds[w][p * 72 + kb * 32 + q * 8];

  // a_src (f16), a_dst (f32), v (f32)
#pragma unroll
  for (int nb = 0; nb < 4; ++nb) {
    v4f c = {0.f, 0.f, 0.f, 0.f};
    c = __builtin_amdgcn_mfma_f32_16x16x32_f16(hA[0], *(const v8h*)&FWsrc[fr_off(0, nb, q, p)], c, 0, 0, 0);
    c = __builtin_amdgcn_mfma_f32_16x16x32_f16(hA[1], *(const v8h*)&FWsrc[fr_off(1, nb, q, p)], c, 0, 0, 0);
#pragma unroll
    for (int r = 0; r < 4; ++r)
      asrch[(base + q * 4 + r) * 64 + p + 16 * nb] = (f16)c[r];
  }
#pragma unroll
  for (int nb = 0; nb < 4; ++nb) {
    v4f c = {0.f, 0.f, 0.f, 0.f};
    c = __builtin_amdgcn_mfma_f32_16x16x32_f16(hA[0], *(const v8h*)&FWdst[fr_off(0, nb, q, p)], c, 0, 0, 0);
    c = __builtin_amdgcn_mfma_f32_16x16x32_f16(hA[1], *(const v8h*)&FWdst[fr_off(1, nb, q, p)], c, 0, 0, 0);
#pragma unroll
    for (int r = 0; r < 4; ++r)
      a_dst[(base + q * 4 + r) * 64 + p + 16 * nb] = c[r];
  }
#pragma unroll
  for (int nb = 0; nb < 4; ++nb) {
    v4f c = {0.f, 0.f, 0.f, 0.f};
    c = __builtin_amdgcn_mfma_f32_16x16x32_f16(hA[0], *(const v8h*)&FWlin[fr_off(0, nb, q, p)], c, 0, 0, 0);
    c = __builtin_amdgcn_mfma_f32_16x16x32_f16(hA[1], *(const v8h*)&FWlin[fr_off(1, nb, q, p)], c, 0, 0, 0);
#pragma unroll
    for (int r = 0; r < 4; ++r)
      vv[(base + q * 4 + r) * 64 + p + 16 * nb] = c[r];
  }
  // Q = pos @ Wp1 (K padded to 32)
  v8h pa;
#pragma unroll
  for (int i = 0; i < 8; ++i) {
    const int k = q * 8 + i;
    pa[i] = (k < 6) ? (f16)pos[(base + p) * 6 + k] : (f16)0.f;
  }
#pragma unroll
  for (int nb = 0; nb < 4; ++nb) {
    const v8h b = *(const v8h*)&FWp1[(((nb * 4 + q) * 16) + p) * 8];
    v4f c = {0.f, 0.f, 0.f, 0.f};
    c = __builtin_amdgcn_mfma_f32_16x16x32_f16(pa, b, c, 0, 0, 0);
#pragma unroll
    for (int r = 0; r < 4; ++r)
      Qh[(base + q * 4 + r) * 64 + p + 16 * nb] = (f16)c[r];
  }
}

// ---------------- conv: wave = dst node, MFMA over 16-edge chunks ----------------
// Weights staged in LDS. __launch_bounds__(256,3): ~170-reg cap — live state
// (~130) fits with NO spills (round-5's (256,4)=128-cap spilled 2 GB to scratch),
// while 3 blocks/CU doubles round-4's occupancy.

__global__ __launch_bounds__(256, 3) void k_conv(
    const f16* __restrict__ Qh, const float* __restrict__ bp1,
    const f16* __restrict__ FRconv,  // Wp2|Wa1|Wa2 frag-layout, 12288 f16
    const float* __restrict__ bp2, const float* __restrict__ ba1,
    const float* __restrict__ ba2,
    const f16* __restrict__ asrch, const float* __restrict__ a_dst,
    const float* __restrict__ v,
    const int* __restrict__ offsets, const int* __restrict__ ssrc,
    float* __restrict__ o_pt) {
  __shared__ f16 wfr[12288];      // 24 KB: Wp2, Wa1, Wa2 fragment images
  __shared__ f16 tbuf[4][16 * 72];  // per-wave transpose buffer (reused)
  const int t = threadIdx.x;
#pragma unroll
  for (int it = 0; it < 6; ++it)
    *(uint4*)&wfr[(it * 256 + t) * 8] = *(const uint4*)&FRconv[(it * 256 + t) * 8];
  __syncthreads();

  const int lane = t & 63, w = t >> 6;
  const int q = lane >> 4, p = lane & 15;
  const int n = blockIdx.x * 4 + w;  // grid = NN/4 exactly

  float bp2C[4], ba1C[4], ba2C[4];
#pragma unroll
  for (int nb = 0; nb < 4; ++nb) {
    bp2C[nb] = bp2[p + 16 * nb];
    ba1C[nb] = ba1[p + 16 * nb];
    ba2C[nb] = ba2[p + 16 * nb];
  }
  // node-i quantities in A-layout channels (ch = kb*32 + q*8 + i)
  v8h Qi8[2];
  float adcA[16];
#pragma unroll
  for (int kb = 0; kb < 2; ++kb) {
    const v8h qv = *(const v8h*)(Qh + n * 64 + kb * 32 + q * 8);
    const float4 b0 = *(const float4*)(bp1 + kb * 32 + q * 8);
    const float4 b1 = *(const float4*)(bp1 + kb * 32 + q * 8 + 4);
    v8h a;
    a[0] = (f16)((float)qv[0] + b0.x); a[1] = (f16)((float)qv[1] + b0.y);
    a[2] = (f16)((float)qv[2] + b0.z); a[3] = (f16)((float)qv[3] + b0.w);
    a[4] = (f16)((float)qv[4] + b1.x); a[5] = (f16)((float)qv[5] + b1.y);
    a[6] = (f16)((float)qv[6] + b1.z); a[7] = (f16)((float)qv[7] + b1.w);
    Qi8[kb] = a;
    const float4 d0 = *(const float4*)(a_dst + n * 64 + kb * 32 + q * 8);
    const float4 d1 = *(const float4*)(a_dst + n * 64 + kb * 32 + q * 8 + 4);
    adcA[kb * 8 + 0] = d0.x; adcA[kb * 8 + 1] = d0.y;
    adcA[kb * 8 + 2] = d0.z; adcA[kb * 8 + 3] = d0.w;
    adcA[kb * 8 + 4] = d1.x; adcA[kb * 8 + 5] = d1.y;
    adcA[kb * 8 + 6] = d1.z; adcA[kb * 8 + 7] = d1.w;
  }
  const int e0 = __builtin_amdgcn_readfirstlane(offsets[n]);
  const int e1 = __builtin_amdgcn_readfirstlane(offsets[n + 1]);
  const int cnt = e1 - e0;

  float m_[4], s_[4], ac_[4];
#pragma unroll
  for (int nb = 0; nb < 4; ++nb) { m_[nb] = 0.f; s_[nb] = 0.f; ac_[nb] = 0.f; }

  for (int cb = 0; cb < cnt; cb += 16) {
    const int jA = ssrc[e0 + min(cb + p, cnt - 1)];  // A-layout edge = p
    int jC[4]; bool okC[4];
#pragma unroll
    for (int r = 0; r < 4; ++r) {  // C-layout edges = q*4+r
      const int tt = cb + q * 4 + r;
      okC[r] = tt < cnt;
      jC[r] = ssrc[e0 + min(tt, cnt - 1)];
    }
    // hp = relu((Qi+bp1) - Qj)  in A layout, packed f16
    v8h uA[2];
#pragma unroll
    for (int kb = 0; kb < 2; ++kb) {
      const v8h qj = *(const v8h*)(Qh + jA * 64 + kb * 32 + q * 8);
      v8h a;
#pragma unroll
      for (int i = 0; i < 8; ++i) {
        const f16 d = Qi8[kb][i] - qj[i];
        a[i] = d > (f16)0 ? d : (f16)0;
      }
      uA[kb] = a;
    }
    // delta = relu(hp @ Wp2 + bp2)  (C layout); stash + LDS transpose
    float deltaC[16];
#pragma unroll
    for (int nb = 0; nb < 4; ++nb) {
      v4f c = {0.f, 0.f, 0.f, 0.f};
      c = __builtin_amdgcn_mfma_f32_16x16x32_f16(uA[0], *(const v8h*)&wfr[fr_off(0, nb, q, p)], c, 0, 0, 0);
      c = __builtin_amdgcn_mfma_f32_16x16x32_f16(uA[1], *(const v8h*)&wfr[fr_off(1, nb, q, p)], c, 0, 0, 0);
#pragma unroll
      for (int r = 0; r < 4; ++r) {
        const float d = fmaxf(c[r] + bp2C[nb], 0.f);
        deltaC[nb * 4 + r] = d;
        tbuf[w][(q * 4 + r) * 72 + p + 16 * nb] = (f16)d;
      }
    }
    // u = a_dst_i - a_src_j + delta  in A layout (f32 math, f16 out)
#pragma unroll
    for (int kb = 0; kb < 2; ++kb) {
      const v8h dj = *(const v8h*)&tbuf[w][p * 72 + kb * 32 + q * 8];
      const v8h aj = *(const v8h*)(asrch + jA * 64 + kb * 32 + q * 8);
      v8h a;
#pragma unroll
      for (int i = 0; i < 8; ++i)
        a[i] = (f16)((adcA[kb * 8 + i] - (float)aj[i]) + (float)dj[i]);
      uA[kb] = a;
    }
    // ha = relu(u @ Wa1 + ba1) -> LDS transpose -> A layout
#pragma unroll
    for (int nb = 0; nb < 4; ++nb) {
      v4f c = {0.f, 0.f, 0.f, 0.f};
      c = __builtin_amdgcn_mfma_f32_16x16x32_f16(uA[0], *(const v8h*)&wfr[4096 + fr_off(0, nb, q, p)], c, 0, 0, 0);
      c = __builtin_amdgcn_mfma_f32_16x16x32_f16(uA[1], *(const v8h*)&wfr[4096 + fr_off(1, nb, q, p)], c, 0, 0, 0);
#pragma unroll
      for (int r = 0; r < 4; ++r)
        tbuf[w][(q * 4 + r) * 72 + p + 16 * nb] = (f16)fmaxf(c[r] + ba1C[nb], 0.f);
    }
#pragma unroll
    for (int kb = 0; kb < 2; ++kb)
      uA[kb] = *(const v8h*)&tbuf[w][p * 72 + kb * 32 + q * 8];
    // alpha = relu(ha @ Wa2 + ba2)  (C layout) + masked online softmax
#pragma unroll
    for (int nb = 0; nb < 4; ++nb) {
      v4f c = {0.f, 0.f, 0.f, 0.f};
      c = __builtin_amdgcn_mfma_f32_16x16x32_f16(uA[0], *(const v8h*)&wfr[8192 + fr_off(0, nb, q, p)], c, 0, 0, 0);
      c = __builtin_amdgcn_mfma_f32_16x16x32_f16(uA[1], *(const v8h*)&wfr[8192 + fr_off(1, nb, q, p)], c, 0, 0, 0);
      float al[4];
#pragma unroll
      for (int r = 0; r < 4; ++r)
        al[r] = okC[r] ? fmaxf(c[r] + ba2C[nb], 0.f) : -3.0e38f;
      float mn = m_[nb];
#pragma unroll
      for (int r = 0; r < 4; ++r) mn = fmaxf(mn, al[r]);
      const float sc = __expf(m_[nb] - mn);
      float ss = s_[nb] * sc;
      float aa = ac_[nb] * sc;
#pragma unroll
      for (int r = 0; r < 4; ++r) {
        const float wv = __expf(al[r] - mn);  // 0 for masked edges
        const float vj = v[jC[r] * 64 + p + 16 * nb];
        ss += wv;
        aa = fmaf(wv, vj + deltaC[nb * 4 + r], aa);
      }
      m_[nb] = mn; s_[nb] = ss; ac_[nb] = aa;
    }
  }
  // merge per-quad partial softmax states (channels identical across quads)
#pragma unroll
  for (int st = 16; st <= 32; st <<= 1) {
#pragma unroll
    for (int nb = 0; nb < 4; ++nb) {
      const float mo = __shfl_xor(m_[nb], st, 64);
      const float so = __shfl_xor(s_[nb], st, 64);
      const float ao = __shfl_xor(ac_[nb], st, 64);
      const float mn = fmaxf(m_[nb], mo);
      const float c1 = __expf(m_[nb] - mn), c2 = __expf(mo - mn);
      s_[nb] = s_[nb] * c1 + so * c2;
      ac_[nb] = ac_[nb] * c1 + ao * c2;
      m_[nb] = mn;
    }
  }
  if (q == 0) {
#pragma unroll
    for (int nb = 0; nb < 4; ++nb)
      o_pt[n * 64 + p + 16 * nb] = ac_[nb] / (s_[nb] + 1e-16f);
  }
}

// ---------------- epilogue (MFMA): out = relu(o_pt @ W_out + b_out) + x ------------

__global__ __launch_bounds__(256, 2) void k_out(
    const float* __restrict__ o_pt, const f16* __restrict__ FR,
    const float* __restrict__ b_out, const float* __restrict__ x,
    float* __restrict__ out) {
  const int lane = threadIdx.x & 63, w = threadIdx.x >> 6;
  const int q = lane >> 4, p = lane & 15;
  const int base = (blockIdx.x * 4 + w) * 16;
  if (base >= NN) return;
  const f16* FWout = FR + 4 * 4096;  // m=4
  v8h oa[2];
#pragma unroll
  for (int kb = 0; kb < 2; ++kb) {
    const float4 f0 = *(const float4*)(o_pt + (base + p) * 64 + kb * 32 + q * 8);
    const float4 f1 = *(const float4*)(o_pt + (base + p) * 64 + kb * 32 + q * 8 + 4);
    v8h a;
    a[0] = (f16)f0.x; a[1] = (f16)f0.y; a[2] = (f16)f0.z; a[3] = (f16)f0.w;
    a[4] = (f16)f1.x; a[5] = (f16)f1.y; a[6] = (f16)f1.z; a[7] = (f16)f1.w;
    oa[kb] = a;
  }
#pragma unroll
  for (int nb = 0; nb < 4; ++nb) {
    v4f c = {0.f, 0.f, 0.f, 0.f};
    c = __builtin_amdgcn_mfma_f32_16x16x32_f16(oa[0], *(const v8h*)&FWout[fr_off(0, nb, q, p)], c, 0, 0, 0);
    c = __builtin_amdgcn_mfma_f32_16x16x32_f16(oa[1], *(const v8h*)&FWout[fr_off(1, nb, q, p)], c, 0, 0, 0);
    const float bo = b_out[p + 16 * nb];
#pragma unroll
    for (int r = 0; r < 4; ++r) {
      const int idx = (base + q * 4 + r) * 64 + p + 16 * nb;
      out[idx] = fmaxf(c[r] + bo, 0.f) + x[idx];
    }
  }
}

// ---------------- launch ----------------

extern "C" void kernel_launch(void* const* d_in, const int* in_sizes, int n_in,
                              void* d_out, int out_size, void* d_ws, size_t ws_size,
                              hipStream_t stream) {
  const float* x     = (const float*)d_in[0];
  const float* pos   = (const float*)d_in[1];
  const int*   ei    = (const int*)d_in[2];
  const float* W_in  = (const float*)d_in[3];
  const float* b_in  = (const float*)d_in[4];
  const float* W_out = (const float*)d_in[5];
  const float* b_out = (const float*)d_in[6];
  const float* W_lin = (const float*)d_in[7];
  const float* W_src = (const float*)d_in[8];
  const float* W_dst = (const float*)d_in[9];
  const float* Wp1   = (const float*)d_in[10];
  const float* bp1   = (const float*)d_in[11];
  const float* Wp2   = (const float*)d_in[12];
  const float* bp2   = (const float*)d_in[13];
  const float* Wa1   = (const float*)d_in[14];
  const float* ba1   = (const float*)d_in[15];
  const float* Wa2   = (const float*)d_in[16];
  const float* ba2   = (const float*)d_in[17];

  float* a_dst = (float*)d_ws;                 // NN*64 f32
  float* vv    = a_dst + NN * 64;              // NN*64 f32
  float* o_pt  = vv + NN * 64;                 // NN*64 f32
  f16*  Qh     = (f16*)(o_pt + NN * 64);       // NN*64 f16
  f16*  asrch  = Qh + NN * 64;                 // NN*64 f16
  f16*  FR     = asrch + NN * 64;              // 8*4096 + 2048 f16 (16B aligned)
  int*  deg    = (int*)(FR + 8 * 4096 + 2048); // NN
  int* offsets = deg + NN;                     // NN+1
  int* cursor  = offsets + NN + 1;             // NN
  int* ssrc    = cursor + NN;                  // ETOT

  const int* esrc = ei;
  const int* edst = ei + NE;

  k_wprep<<<(8 * 4096 + 2048 + 255) / 256, 256, 0, stream>>>(
      W_in, W_src, W_dst, W_lin, W_out, Wp2, Wa1, Wa2, Wp1, FR);
  k_deg_init<<<(NN + 255) / 256, 256, 0, stream>>>(deg);
  k_node<<<(NN / 16 + 3) / 4, 256, 0, stream>>>(x, pos, b_in, FR, a_dst, vv, asrch, Qh);
  k_deg<<<(NE + 255) / 256, 256, 0, stream>>>(edst, deg);
  k_scan<<<1, 1024, 0, stream>>>(deg, offsets, ssrc, cursor);
  k_scatter<<<(NE + 255) / 256, 256, 0, stream>>>(esrc, edst, cursor, ssrc);
  k_conv<<<NN / 4, 256, 0, stream>>>(Qh, bp1, FR + 5 * 4096, bp2, ba1, ba2,
                                     asrch, a_dst, vv, offsets, ssrc, o_pt);
  k_out<<<(NN / 16 + 3) / 4, 256, 0, stream>>>(o_pt, FR, b_out, x, (float*)d_out);
}

// Round 7
// 477.508 us; speedup vs baseline: 1.5060x; 1.2210x over previous
//
#include <hip/hip_runtime.h>

#define NN 50000
#define NE 800000
#define ETOT (NE + NN)

typedef _Float16 f16;
typedef _Float16 v8h __attribute__((ext_vector_type(8)));
typedef float v4f __attribute__((ext_vector_type(4)));

// fragment-layout index for a 64x64 matrix, mfma_f32_16x16x32 B-operand:
// FR[(((nb*2+kb)*4+q)*16+p)*8 + i] = W[(kb*32+q*8+i)*64 + nb*16+p]
__device__ __forceinline__ int fr_off(int kb, int nb, int q, int p) {
  return (((nb * 2 + kb) * 4 + q) * 16 + p) * 8;
}

// ---------------- weight pre-conversion to f16 fragment layout ----------------

__global__ __launch_bounds__(256) void k_wprep(
    const float* __restrict__ W_in, const float* __restrict__ W_src,
    const float* __restrict__ W_dst, const float* __restrict__ W_lin,
    const float* __restrict__ W_out, const float* __restrict__ Wp2,
    const float* __restrict__ Wa1, const float* __restrict__ Wa2,
    const float* __restrict__ Wp1, f16* __restrict__ FR) {
  const int t = blockIdx.x * 256 + threadIdx.x;
  if (t < 8 * 4096) {
    const float* Ws[8] = {W_in, W_src, W_dst, W_lin, W_out, Wp2, Wa1, Wa2};
    const int m = t >> 12, idx = t & 4095;
    const int i = idx & 7, p = (idx >> 3) & 15, q = (idx >> 7) & 3;
    const int kb = (idx >> 9) & 1, nb = (idx >> 10) & 3;
    FR[t] = (f16)Ws[m][(kb * 32 + q * 8 + i) * 64 + nb * 16 + p];
  } else if (t < 8 * 4096 + 2048) {
    const int idx = t - 8 * 4096;
    const int i = idx & 7, p = (idx >> 3) & 15, q = (idx >> 7) & 3, nb = idx >> 9;
    const int k = q * 8 + i;
    FR[t] = (k < 6) ? (f16)Wp1[k * 64 + nb * 16 + p] : (f16)0.f;
  }
}

// ---------------- CSR build ----------------

__global__ void k_deg_init(int* __restrict__ deg) {
  int i = blockIdx.x * 256 + threadIdx.x;
  if (i < NN) deg[i] = 1;  // self loop
}

__global__ void k_deg(const int* __restrict__ dst, int* __restrict__ deg) {
  int e = blockIdx.x * 256 + threadIdx.x;
  if (e < NE) atomicAdd(&deg[dst[e]], 1);
}

__global__ void k_scan(const int* __restrict__ deg, int* __restrict__ offsets,
                       int* __restrict__ ssrc, int* __restrict__ cursor) {
  __shared__ int wsum[16];
  __shared__ int carry;
  const int t = threadIdx.x, lane = t & 63, w = t >> 6;
  if (t == 0) carry = 0;
  __syncthreads();
  for (int base = 0; base < NN; base += 1024) {
    const int i = base + t;
    int v = (i < NN) ? deg[i] : 0;
    int x = v;
#pragma unroll
    for (int d = 1; d < 64; d <<= 1) {
      int y = __shfl_up(x, d, 64);
      if (lane >= d) x += y;
    }
    if (lane == 63) wsum[w] = x;
    __syncthreads();
    if (t < 16) {
      int z = wsum[t];
#pragma unroll
      for (int d = 1; d < 16; d <<= 1) {
        int y = __shfl_up(z, d, 64);
        if (t >= d) z += y;
      }
      wsum[t] = z;
    }
    __syncthreads();
    const int cb = carry;
    const int prev = (w > 0) ? wsum[w - 1] : 0;
    if (i < NN) {
      const int off = cb + prev + x - v;  // exclusive
      offsets[i] = off;
      ssrc[off] = i;        // self loop first in segment
      cursor[i] = off + 1;
    }
    const int ctot = wsum[15];
    __syncthreads();
    if (t == 0) carry = cb + ctot;
    __syncthreads();
  }
  if (t == 0) offsets[NN] = carry;
}

__global__ void k_scatter(const int* __restrict__ src, const int* __restrict__ dst,
                          int* __restrict__ cursor, int* __restrict__ ssrc) {
  int e = blockIdx.x * 256 + threadIdx.x;
  if (e < NE) {
    int p = atomicAdd(&cursor[dst[e]], 1);
    ssrc[p] = src[e];
  }
}

// ---------------- node projections (MFMA): h; a_src/a_dst(f16)/v; Q = pos@Wp1 -------

__global__ __launch_bounds__(256, 2) void k_node(
    const float* __restrict__ x, const float* __restrict__ pos,
    const float* __restrict__ b_in, const f16* __restrict__ FR,
    f16* __restrict__ adsth, float* __restrict__ vv,
    f16* __restrict__ asrch, f16* __restrict__ Qh) {
  __shared__ f16 lds[4][16 * 72];
  const int lane = threadIdx.x & 63, w = threadIdx.x >> 6;
  const int q = lane >> 4, p = lane & 15;
  const int base = (blockIdx.x * 4 + w) * 16;
  if (base >= NN) return;
  const f16* FWin = FR;                 // m=0
  const f16* FWsrc = FR + 1 * 4096;     // m=1
  const f16* FWdst = FR + 2 * 4096;     // m=2
  const f16* FWlin = FR + 3 * 4096;     // m=3
  const f16* FWp1 = FR + 8 * 4096;      // kb=0 only

  v8h xa[2];
#pragma unroll
  for (int kb = 0; kb < 2; ++kb) {
    const float4 f0 = *(const float4*)(x + (base + p) * 64 + kb * 32 + q * 8);
    const float4 f1 = *(const float4*)(x + (base + p) * 64 + kb * 32 + q * 8 + 4);
    v8h a;
    a[0] = (f16)f0.x; a[1] = (f16)f0.y; a[2] = (f16)f0.z; a[3] = (f16)f0.w;
    a[4] = (f16)f1.x; a[5] = (f16)f1.y; a[6] = (f16)f1.z; a[7] = (f16)f1.w;
    xa[kb] = a;
  }
  // h = relu(x@W_in + b_in) -> LDS (C->A transpose)
#pragma unroll
  for (int nb = 0; nb < 4; ++nb) {
    v4f c = {0.f, 0.f, 0.f, 0.f};
    c = __builtin_amdgcn_mfma_f32_16x16x32_f16(xa[0], *(const v8h*)&FWin[fr_off(0, nb, q, p)], c, 0, 0, 0);
    c = __builtin_amdgcn_mfma_f32_16x16x32_f16(xa[1], *(const v8h*)&FWin[fr_off(1, nb, q, p)], c, 0, 0, 0);
    const float bi = b_in[p + 16 * nb];
#pragma unroll
    for (int r = 0; r < 4; ++r)
      lds[w][(q * 4 + r) * 72 + p + 16 * nb] = (f16)fmaxf(c[r] + bi, 0.f);
  }
  v8h hA[2];
#pragma unroll
  for (int kb = 0; kb < 2; ++kb)
    hA[kb] = *(const v8h*)&lds[w][p * 72 + kb * 32 + q * 8];

  // a_src (f16), a_dst (f16), v (f32)
#pragma unroll
  for (int nb = 0; nb < 4; ++nb) {
    v4f c = {0.f, 0.f, 0.f, 0.f};
    c = __builtin_amdgcn_mfma_f32_16x16x32_f16(hA[0], *(const v8h*)&FWsrc[fr_off(0, nb, q, p)], c, 0, 0, 0);
    c = __builtin_amdgcn_mfma_f32_16x16x32_f16(hA[1], *(const v8h*)&FWsrc[fr_off(1, nb, q, p)], c, 0, 0, 0);
#pragma unroll
    for (int r = 0; r < 4; ++r)
      asrch[(base + q * 4 + r) * 64 + p + 16 * nb] = (f16)c[r];
  }
#pragma unroll
  for (int nb = 0; nb < 4; ++nb) {
    v4f c = {0.f, 0.f, 0.f, 0.f};
    c = __builtin_amdgcn_mfma_f32_16x16x32_f16(hA[0], *(const v8h*)&FWdst[fr_off(0, nb, q, p)], c, 0, 0, 0);
    c = __builtin_amdgcn_mfma_f32_16x16x32_f16(hA[1], *(const v8h*)&FWdst[fr_off(1, nb, q, p)], c, 0, 0, 0);
#pragma unroll
    for (int r = 0; r < 4; ++r)
      adsth[(base + q * 4 + r) * 64 + p + 16 * nb] = (f16)c[r];
  }
#pragma unroll
  for (int nb = 0; nb < 4; ++nb) {
    v4f c = {0.f, 0.f, 0.f, 0.f};
    c = __builtin_amdgcn_mfma_f32_16x16x32_f16(hA[0], *(const v8h*)&FWlin[fr_off(0, nb, q, p)], c, 0, 0, 0);
    c = __builtin_amdgcn_mfma_f32_16x16x32_f16(hA[1], *(const v8h*)&FWlin[fr_off(1, nb, q, p)], c, 0, 0, 0);
#pragma unroll
    for (int r = 0; r < 4; ++r)
      vv[(base + q * 4 + r) * 64 + p + 16 * nb] = c[r];
  }
  // Q = pos @ Wp1 (K padded to 32)
  v8h pa;
#pragma unroll
  for (int i = 0; i < 8; ++i) {
    const int k = q * 8 + i;
    pa[i] = (k < 6) ? (f16)pos[(base + p) * 6 + k] : (f16)0.f;
  }
#pragma unroll
  for (int nb = 0; nb < 4; ++nb) {
    const v8h b = *(const v8h*)&FWp1[(((nb * 4 + q) * 16) + p) * 8];
    v4f c = {0.f, 0.f, 0.f, 0.f};
    c = __builtin_amdgcn_mfma_f32_16x16x32_f16(pa, b, c, 0, 0, 0);
#pragma unroll
    for (int r = 0; r < 4; ++r)
      Qh[(base + q * 4 + r) * 64 + p + 16 * nb] = (f16)c[r];
  }
}

// ---------------- conv: wave = dst node, MFMA over 16-edge chunks ----------------
// Weights in LDS; delta round-trips through its own LDS buffer (not registers);
// a_dst carried as f16 — persistent register state ~55, fits (256,3)'s ~170 cap
// with no spills (round-6: deltaC[16]+adcA[16] in regs spilled 525 MB/dispatch).

__global__ __launch_bounds__(256, 3) void k_conv(
    const f16* __restrict__ Qh, const float* __restrict__ bp1,
    const f16* __restrict__ FRconv,  // Wp2|Wa1|Wa2 frag-layout, 12288 f16
    const float* __restrict__ bp2, const float* __restrict__ ba1,
    const float* __restrict__ ba2,
    const f16* __restrict__ asrch, const f16* __restrict__ adsth,
    const float* __restrict__ v,
    const int* __restrict__ offsets, const int* __restrict__ ssrc,
    float* __restrict__ o_pt) {
  __shared__ f16 wfr[12288];         // 24 KB: Wp2, Wa1, Wa2 fragment images
  __shared__ f16 tbufD[4][16 * 72];  // per-wave delta buffer (C layout)
  __shared__ f16 tbufH[4][16 * 72];  // per-wave ha transpose buffer
  const int t = threadIdx.x;
#pragma unroll
  for (int it = 0; it < 6; ++it)
    *(uint4*)&wfr[(it * 256 + t) * 8] = *(const uint4*)&FRconv[(it * 256 + t) * 8];
  __syncthreads();

  const int lane = t & 63, w = t >> 6;
  const int q = lane >> 4, p = lane & 15;
  const int n = blockIdx.x * 4 + w;  // grid = NN/4 exactly

  float bp2C[4], ba1C[4], ba2C[4];
#pragma unroll
  for (int nb = 0; nb < 4; ++nb) {
    bp2C[nb] = bp2[p + 16 * nb];
    ba1C[nb] = ba1[p + 16 * nb];
    ba2C[nb] = ba2[p + 16 * nb];
  }
  // node-i quantities in A-layout channels (ch = kb*32 + q*8 + i), packed f16
  v8h Qi8[2], adcH[2];
#pragma unroll
  for (int kb = 0; kb < 2; ++kb) {
    const v8h qv = *(const v8h*)(Qh + n * 64 + kb * 32 + q * 8);
    const float4 b0 = *(const float4*)(bp1 + kb * 32 + q * 8);
    const float4 b1 = *(const float4*)(bp1 + kb * 32 + q * 8 + 4);
    v8h a;
    a[0] = (f16)((float)qv[0] + b0.x); a[1] = (f16)((float)qv[1] + b0.y);
    a[2] = (f16)((float)qv[2] + b0.z); a[3] = (f16)((float)qv[3] + b0.w);
    a[4] = (f16)((float)qv[4] + b1.x); a[5] = (f16)((float)qv[5] + b1.y);
    a[6] = (f16)((float)qv[6] + b1.z); a[7] = (f16)((float)qv[7] + b1.w);
    Qi8[kb] = a;
    adcH[kb] = *(const v8h*)(adsth + n * 64 + kb * 32 + q * 8);
  }
  const int e0 = __builtin_amdgcn_readfirstlane(offsets[n]);
  const int e1 = __builtin_amdgcn_readfirstlane(offsets[n + 1]);
  const int cnt = e1 - e0;

  float m_[4], s_[4], ac_[4];
#pragma unroll
  for (int nb = 0; nb < 4; ++nb) { m_[nb] = 0.f; s_[nb] = 0.f; ac_[nb] = 0.f; }

  for (int cb = 0; cb < cnt; cb += 16) {
    const int jA = ssrc[e0 + min(cb + p, cnt - 1)];  // A-layout edge = p
    int jC[4]; bool okC[4];
#pragma unroll
    for (int r = 0; r < 4; ++r) {  // C-layout edges = q*4+r
      const int tt = cb + q * 4 + r;
      okC[r] = tt < cnt;
      jC[r] = ssrc[e0 + min(tt, cnt - 1)];
    }
    // hp = relu((Qi+bp1) - Qj)  in A layout, packed f16
    v8h uA[2];
#pragma unroll
    for (int kb = 0; kb < 2; ++kb) {
      const v8h qj = *(const v8h*)(Qh + jA * 64 + kb * 32 + q * 8);
      v8h a;
#pragma unroll
      for (int i = 0; i < 8; ++i) {
        const f16 d = Qi8[kb][i] - qj[i];
        a[i] = d > (f16)0 ? d : (f16)0;
      }
      uA[kb] = a;
    }
    // delta = relu(hp @ Wp2 + bp2)  (C layout) -> tbufD only (no register copy)
#pragma unroll
    for (int nb = 0; nb < 4; ++nb) {
      v4f c = {0.f, 0.f, 0.f, 0.f};
      c = __builtin_amdgcn_mfma_f32_16x16x32_f16(uA[0], *(const v8h*)&wfr[fr_off(0, nb, q, p)], c, 0, 0, 0);
      c = __builtin_amdgcn_mfma_f32_16x16x32_f16(uA[1], *(const v8h*)&wfr[fr_off(1, nb, q, p)], c, 0, 0, 0);
#pragma unroll
      for (int r = 0; r < 4; ++r)
        tbufD[w][(q * 4 + r) * 72 + p + 16 * nb] = (f16)fmaxf(c[r] + bp2C[nb], 0.f);
    }
    // u = a_dst_i - a_src_j + delta  in A layout (packed f16 math)
#pragma unroll
    for (int kb = 0; kb < 2; ++kb) {
      const v8h dj = *(const v8h*)&tbufD[w][p * 72 + kb * 32 + q * 8];
      const v8h aj = *(const v8h*)(asrch + jA * 64 + kb * 32 + q * 8);
      uA[kb] = (adcH[kb] - aj) + dj;
    }
    // ha = relu(u @ Wa1 + ba1) -> tbufH -> A layout
#pragma unroll
    for (int nb = 0; nb < 4; ++nb) {
      v4f c = {0.f, 0.f, 0.f, 0.f};
      c = __builtin_amdgcn_mfma_f32_16x16x32_f16(uA[0], *(const v8h*)&wfr[4096 + fr_off(0, nb, q, p)], c, 0, 0, 0);
      c = __builtin_amdgcn_mfma_f32_16x16x32_f16(uA[1], *(const v8h*)&wfr[4096 + fr_off(1, nb, q, p)], c, 0, 0, 0);
#pragma unroll
      for (int r = 0; r < 4; ++r)
        tbufH[w][(q * 4 + r) * 72 + p + 16 * nb] = (f16)fmaxf(c[r] + ba1C[nb], 0.f);
    }
#pragma unroll
    for (int kb = 0; kb < 2; ++kb)
      uA[kb] = *(const v8h*)&tbufH[w][p * 72 + kb * 32 + q * 8];
    // alpha = relu(ha @ Wa2 + ba2)  (C layout) + masked online softmax
#pragma unroll
    for (int nb = 0; nb < 4; ++nb) {
      v4f c = {0.f, 0.f, 0.f, 0.f};
      c = __builtin_amdgcn_mfma_f32_16x16x32_f16(uA[0], *(const v8h*)&wfr[8192 + fr_off(0, nb, q, p)], c, 0, 0, 0);
      c = __builtin_amdgcn_mfma_f32_16x16x32_f16(uA[1], *(const v8h*)&wfr[8192 + fr_off(1, nb, q, p)], c, 0, 0, 0);
      float al[4];
#pragma unroll
      for (int r = 0; r < 4; ++r)
        al[r] = okC[r] ? fmaxf(c[r] + ba2C[nb], 0.f) : -3.0e38f;
      float mn = m_[nb];
#pragma unroll
      for (int r = 0; r < 4; ++r) mn = fmaxf(mn, al[r]);
      const float sc = __expf(m_[nb] - mn);
      float ss = s_[nb] * sc;
      float aa = ac_[nb] * sc;
#pragma unroll
      for (int r = 0; r < 4; ++r) {
        const float wv = __expf(al[r] - mn);  // 0 for masked edges
        const float vj = v[jC[r] * 64 + p + 16 * nb];
        const float dC = (float)tbufD[w][(q * 4 + r) * 72 + p + 16 * nb];
        ss += wv;
        aa = fmaf(wv, vj + dC, aa);
      }
      m_[nb] = mn; s_[nb] = ss; ac_[nb] = aa;
    }
  }
  // merge per-quad partial softmax states (channels identical across quads)
#pragma unroll
  for (int st = 16; st <= 32; st <<= 1) {
#pragma unroll
    for (int nb = 0; nb < 4; ++nb) {
      const float mo = __shfl_xor(m_[nb], st, 64);
      const float so = __shfl_xor(s_[nb], st, 64);
      const float ao = __shfl_xor(ac_[nb], st, 64);
      const float mn = fmaxf(m_[nb], mo);
      const float c1 = __expf(m_[nb] - mn), c2 = __expf(mo - mn);
      s_[nb] = s_[nb] * c1 + so * c2;
      ac_[nb] = ac_[nb] * c1 + ao * c2;
      m_[nb] = mn;
    }
  }
  if (q == 0) {
#pragma unroll
    for (int nb = 0; nb < 4; ++nb)
      o_pt[n * 64 + p + 16 * nb] = ac_[nb] / (s_[nb] + 1e-16f);
  }
}

// ---------------- epilogue (MFMA): out = relu(o_pt @ W_out + b_out) + x ------------

__global__ __launch_bounds__(256, 2) void k_out(
    const float* __restrict__ o_pt, const f16* __restrict__ FR,
    const float* __restrict__ b_out, const float* __restrict__ x,
    float* __restrict__ out) {
  const int lane = threadIdx.x & 63, w = threadIdx.x >> 6;
  const int q = lane >> 4, p = lane & 15;
  const int base = (blockIdx.x * 4 + w) * 16;
  if (base >= NN) return;
  const f16* FWout = FR + 4 * 4096;  // m=4
  v8h oa[2];
#pragma unroll
  for (int kb = 0; kb < 2; ++kb) {
    const float4 f0 = *(const float4*)(o_pt + (base + p) * 64 + kb * 32 + q * 8);
    const float4 f1 = *(const float4*)(o_pt + (base + p) * 64 + kb * 32 + q * 8 + 4);
    v8h a;
    a[0] = (f16)f0.x; a[1] = (f16)f0.y; a[2] = (f16)f0.z; a[3] = (f16)f0.w;
    a[4] = (f16)f1.x; a[5] = (f16)f1.y; a[6] = (f16)f1.z; a[7] = (f16)f1.w;
    oa[kb] = a;
  }
#pragma unroll
  for (int nb = 0; nb < 4; ++nb) {
    v4f c = {0.f, 0.f, 0.f, 0.f};
    c = __builtin_amdgcn_mfma_f32_16x16x32_f16(oa[0], *(const v8h*)&FWout[fr_off(0, nb, q, p)], c, 0, 0, 0);
    c = __builtin_amdgcn_mfma_f32_16x16x32_f16(oa[1], *(const v8h*)&FWout[fr_off(1, nb, q, p)], c, 0, 0, 0);
    const float bo = b_out[p + 16 * nb];
#pragma unroll
    for (int r = 0; r < 4; ++r) {
      const int idx = (base + q * 4 + r) * 64 + p + 16 * nb;
      out[idx] = fmaxf(c[r] + bo, 0.f) + x[idx];
    }
  }
}

// ---------------- launch ----------------

extern "C" void kernel_launch(void* const* d_in, const int* in_sizes, int n_in,
                              void* d_out, int out_size, void* d_ws, size_t ws_size,
                              hipStream_t stream) {
  const float* x     = (const float*)d_in[0];
  const float* pos   = (const float*)d_in[1];
  const int*   ei    = (const int*)d_in[2];
  const float* W_in  = (const float*)d_in[3];
  const float* b_in  = (const float*)d_in[4];
  const float* W_out = (const float*)d_in[5];
  const float* b_out = (const float*)d_in[6];
  const float* W_lin = (const float*)d_in[7];
  const float* W_src = (const float*)d_in[8];
  const float* W_dst = (const float*)d_in[9];
  const float* Wp1   = (const float*)d_in[10];
  const float* bp1   = (const float*)d_in[11];
  const float* Wp2   = (const float*)d_in[12];
  const float* bp2   = (const float*)d_in[13];
  const float* Wa1   = (const float*)d_in[14];
  const float* ba1   = (const float*)d_in[15];
  const float* Wa2   = (const float*)d_in[16];
  const float* ba2   = (const float*)d_in[17];

  float* vv    = (float*)d_ws;                 // NN*64 f32
  float* o_pt  = vv + NN * 64;                 // NN*64 f32
  f16*  Qh     = (f16*)(o_pt + NN * 64);       // NN*64 f16
  f16*  asrch  = Qh + NN * 64;                 // NN*64 f16
  f16*  adsth  = asrch + NN * 64;              // NN*64 f16
  f16*  FR     = adsth + NN * 64;              // 8*4096 + 2048 f16
  int*  deg    = (int*)(FR + 8 * 4096 + 2048); // NN
  int* offsets = deg + NN;                     // NN+1
  int* cursor  = offsets + NN + 1;             // NN
  int* ssrc    = cursor + NN;                  // ETOT

  const int* esrc = ei;
  const int* edst = ei + NE;

  k_wprep<<<(8 * 4096 + 2048 + 255) / 256, 256, 0, stream>>>(
      W_in, W_src, W_dst, W_lin, W_out, Wp2, Wa1, Wa2, Wp1, FR);
  k_deg_init<<<(NN + 255) / 256, 256, 0, stream>>>(deg);
  k_node<<<(NN / 16 + 3) / 4, 256, 0, stream>>>(x, pos, b_in, FR, adsth, vv, asrch, Qh);
  k_deg<<<(NE + 255) / 256, 256, 0, stream>>>(edst, deg);
  k_scan<<<1, 1024, 0, stream>>>(deg, offsets, ssrc, cursor);
  k_scatter<<<(NE + 255) / 256, 256, 0, stream>>>(esrc, edst, cursor, ssrc);
  k_conv<<<NN / 4, 256, 0, stream>>>(Qh, bp1, FR + 5 * 4096, bp2, ba1, ba2,
                                     asrch, adsth, vv, offsets, ssrc, o_pt);
  k_out<<<(NN / 16 + 3) / 4, 256, 0, stream>>>(o_pt, FR, b_out, x, (float*)d_out);
}